// Round 6
// baseline (169.650 us; speedup 1.0000x reference)
//
#include <hip/hip_runtime.h>

// ---------------------------------------------------------------------------
// AveragedKeyCircularConvolutionalAttention  (B=2, N=2048, C=768, h=12, d=64)
// 6-node pipeline (memset + 5 kernels). R6: traffic/latency pass —
//   k_conv 256-row tiles (halves 16x-redundant V reads),
//   k_prep slab-contiguous colsum (no strided latency chain),
//   k_ub coalesced K_avg.
//
//  D0 memset : x_avg[2][768] = 0
//  D1 k_prep : x,Wv,Wp -> bf16 ; slab colsum -> atomicAdd x_avg  (512 blk)
//  D2 k_ub   : Ub = SCALE/2048 * (x_avg@Wk^T) @ Wq rows          (24 blk)
//  D3 k_gemms: VT = (x@Wv^T)^T (192 blk) || z_t = (xb@Ub^T)^T (32 blk)
//  D4 k_conv : in-block softmax(z_t) + circulant MFMA -> out_pre (192 blk)
//  D5 k_out  : out = out_pre @ Wp^T + bp  (f32)                  (192 blk)
// ---------------------------------------------------------------------------

typedef __bf16 bf16x8 __attribute__((ext_vector_type(8)));
typedef float  f32x4  __attribute__((ext_vector_type(4)));

#define AS_GLOBAL(p) ((const __attribute__((address_space(1))) unsigned int*)(p))
#define AS_LDS(p)    ((__attribute__((address_space(3))) unsigned int*)(p))

__device__ __forceinline__ void async16(const void* g, void* l) {
    __builtin_amdgcn_global_load_lds(AS_GLOBAL(g), AS_LDS(l), 16, 0, 0);
}

struct bf4 { __bf16 a, b, c, d; };

// ---------------------------------------------------------------------------
// bf16 GEMM tile:  C[m][n] = sum_k A[m][k]*Bt[n][k].  BM=128, BK=32, dbuf.
// MODE 0: bf16 store   MODE 1: f32 + bias   MODE 2: z transposed f32
// ---------------------------------------------------------------------------
template <int BN, int MODE>
__device__ void gemm_phase(char* smem, const __bf16* __restrict__ A,
                           const __bf16* __restrict__ Bt, void* __restrict__ Cout,
                           const float* __restrict__ bias,
                           int K, int ldA, int ldBt, int ldC, int mBase, int nBase)
{
    constexpr int STRIDE = (128 + BN) * 32 * 2;   // bytes per buffer pair
    constexpr int WN = BN / 2, NI = WN / 16;
    const int tid = threadIdx.x;
    const int lane = tid & 63, wid = tid >> 6;
    const int lane15 = lane & 15, quad = lane >> 4;
    const int wm = (wid & 1) * 64, wn = (wid >> 1) * WN;

    auto stage = [&](int kb, int buf) {
        __bf16* As = (__bf16*)(smem + buf * STRIDE);
        __bf16* Bs = As + 128 * 32;
#pragma unroll
        for (int c0 = 0; c0 < 512; c0 += 256) {
            int c = c0 + tid, row = c >> 2, slot = c & 3;
            int k8 = slot ^ ((row >> 1) & 3);
            async16(A + (size_t)(mBase + row) * ldA + kb + k8 * 8, As + c * 8);
        }
#pragma unroll
        for (int c0 = 0; c0 < BN * 4; c0 += 256) {
            int c = c0 + tid, row = c >> 2, slot = c & 3;
            int k8 = slot ^ ((row >> 1) & 3);
            async16(Bt + (size_t)(nBase + row) * ldBt + kb + k8 * 8, Bs + c * 8);
        }
    };

    f32x4 acc[4][NI] = {};
    const int nk = K >> 5;

    stage(0, 0);
    for (int ki = 0; ki < nk; ++ki) {
        __syncthreads();                       // drains stage ki
        if (ki + 1 < nk) stage((ki + 1) << 5, (ki + 1) & 1);

        __bf16* As = (__bf16*)(smem + (ki & 1) * STRIDE);
        __bf16* Bs = As + 128 * 32;
        bf16x8 af[4], bv[NI];
#pragma unroll
        for (int mi = 0; mi < 4; ++mi) {
            int row = wm + mi * 16 + lane15;
            af[mi] = *(const bf16x8*)&As[row * 32 + (quad ^ ((row >> 1) & 3)) * 8];
        }
#pragma unroll
        for (int ni = 0; ni < NI; ++ni) {
            int row = wn + ni * 16 + lane15;
            bv[ni] = *(const bf16x8*)&Bs[row * 32 + (quad ^ ((row >> 1) & 3)) * 8];
        }
#pragma unroll
        for (int mi = 0; mi < 4; ++mi)
#pragma unroll
            for (int ni = 0; ni < NI; ++ni)
                acc[mi][ni] = __builtin_amdgcn_mfma_f32_16x16x32_bf16(
                    af[mi], bv[ni], acc[mi][ni], 0, 0, 0);
    }

#pragma unroll
    for (int mi = 0; mi < 4; ++mi)
#pragma unroll
        for (int ni = 0; ni < NI; ++ni)
#pragma unroll
            for (int r = 0; r < 4; ++r) {
                int row = mBase + wm + mi * 16 + quad * 4 + r;
                int col = nBase + wn + ni * 16 + lane15;
                float v = acc[mi][ni][r];
                if (MODE == 0) {
                    ((__bf16*)Cout)[(size_t)row * ldC + col] = (__bf16)v;
                } else if (MODE == 1) {
                    ((float*)Cout)[(size_t)row * ldC + col] = v + bias[col];
                } else {
                    int b = row >> 11;
                    if ((unsigned)(col - b * 12) < 12u)
                        ((float*)Cout)[(size_t)col * 2048 + (row & 2047)] = v;
                }
            }
}

// ---------------------------------------------------------------------------
// D1: converts + slab colsum.  Block bid owns rows [8*bid, 8*bid+8) of x
// (contiguous 24.6 KB), accumulates columns in LDS, one atomicAdd per col.
// ---------------------------------------------------------------------------
__global__ __launch_bounds__(256)
void k_prep(const float* __restrict__ x, const float* __restrict__ Wv,
            const float* __restrict__ Wp,
            __bf16* __restrict__ xb, __bf16* __restrict__ Wvb,
            __bf16* __restrict__ Wpb, float* __restrict__ x_avg)
{
    const int bid = blockIdx.x, tid = threadIdx.x;
    __shared__ float sums[768];
    for (int c = tid; c < 768; c += 256) sums[c] = 0.f;
    __syncthreads();

    const float4* xs = (const float4*)x + (size_t)bid * 1536;  // 8 rows
    bf4* xd = (bf4*)xb + (size_t)bid * 1536;
#pragma unroll
    for (int r = 0; r < 6; ++r) {
        int j = tid + r * 256;          // < 1536
        float4 v = xs[j];
        xd[j] = bf4{(__bf16)v.x, (__bf16)v.y, (__bf16)v.z, (__bf16)v.w};
        int col = (j % 192) * 4;
        atomicAdd(&sums[col + 0], v.x);
        atomicAdd(&sums[col + 1], v.y);
        atomicAdd(&sums[col + 2], v.z);
        atomicAdd(&sums[col + 3], v.w);
    }
    // weight converts: 512 blocks x 288 f4 = 147456 exactly
    const float4* wv4 = (const float4*)Wv;  bf4* wvb4 = (bf4*)Wvb;
    const float4* wp4 = (const float4*)Wp;  bf4* wpb4 = (bf4*)Wpb;
    for (int t = tid; t < 288; t += 256) {
        int g = bid * 288 + t;
        float4 v = wv4[g];
        wvb4[g] = bf4{(__bf16)v.x, (__bf16)v.y, (__bf16)v.z, (__bf16)v.w};
        float4 w2 = wp4[g];
        wpb4[g] = bf4{(__bf16)w2.x, (__bf16)w2.y, (__bf16)w2.z, (__bf16)w2.w};
    }
    __syncthreads();
    const int b = bid >> 8;             // 256 slabs per batch
    for (int c = tid; c < 768; c += 256)
        atomicAdd(&x_avg[b * 768 + c], sums[c]);
}

// ---------------------------------------------------------------------------
// D2: Ub rows, one block per bh (24).  Coalesced wave-per-row K_avg.
// ---------------------------------------------------------------------------
__global__ __launch_bounds__(256)
void k_ub(const float* __restrict__ x_avg, const float* __restrict__ Wk,
          const float* __restrict__ Wq, __bf16* __restrict__ Ub)
{
    const int bid = blockIdx.x, tid = threadIdx.x;
    const int lane = tid & 63, wid = tid >> 6;
    __shared__ float sx[768];
    __shared__ float sk[64];
    int b = bid / 12, h = bid % 12;
    for (int c = tid; c < 768; c += 256) sx[c] = x_avg[b * 768 + c];
    __syncthreads();
    // K_avg: wave wid handles rows o = round*4 + wid, coalesced 256B loads
    for (int round = 0; round < 16; ++round) {
        int o = round * 4 + wid;
        const float* wk = Wk + (size_t)(h * 64 + o) * 768;
        float s = 0.f;
#pragma unroll
        for (int cc0 = 0; cc0 < 768; cc0 += 64) s += sx[cc0 + lane] * wk[cc0 + lane];
#pragma unroll
        for (int off = 32; off; off >>= 1) s += __shfl_down(s, off);
        if (lane == 0) sk[o] = s * (0.125f / 2048.f);   // fold SCALE and 1/N
    }
    __syncthreads();
    for (int c = tid; c < 768; c += 256) {
        float s = 0.f;
#pragma unroll 16
        for (int d2 = 0; d2 < 64; ++d2)
            s += sk[d2] * Wq[(size_t)(h * 64 + d2) * 768 + c];
        Ub[(size_t)bid * 768 + c] = (__bf16)s;
    }
}

// ---------------------------------------------------------------------------
// D3: VT gemm (blocks 0..191)  ||  z gemm (blocks 192..223)
// NOTE: Ub rows 24..63 hold ws poison; affected z_t cols >=24 are discarded
// by the MODE-2 bound check (independent dot products, no contamination).
// ---------------------------------------------------------------------------
__global__ __launch_bounds__(256, 2)
void k_gemms(const __bf16* __restrict__ xb, const __bf16* __restrict__ Wvb,
             const __bf16* __restrict__ Ub, __bf16* __restrict__ VT,
             float* __restrict__ z_t)
{
    __shared__ __attribute__((aligned(16))) char smem[32768];
    const int bid = blockIdx.x;
    if (bid < 192) {
        gemm_phase<128, 0>(smem, Wvb, xb, VT, nullptr, 768, 768, 768, 4096,
                           (bid / 32) * 128, (bid % 32) * 128);
    } else {
        gemm_phase<64, 2>(smem, xb, Ub, z_t, nullptr, 768, 768, 768, 0,
                          (bid - 192) * 128, 0);
    }
}

// ---------------------------------------------------------------------------
// D4: conv with in-block softmax, dbuf V-tile.  192 blocks: 8 tiles of
// 256 rows x 64 dd per (b,h); each wave owns 64 rows x 64 dd (acc[4][4]).
// smem: rep[8][2056] @0 (32896) | vt0 @32896 (8192, aliases red) |
//       vt1 @41088 (8192) | attn_s @49280 (4096)   total 53376
// ---------------------------------------------------------------------------
__global__ __launch_bounds__(256, 2)
void k_conv(const float* __restrict__ z_t, const __bf16* __restrict__ VT,
            __bf16* __restrict__ outp)
{
    __shared__ __attribute__((aligned(16))) char smem[53376];
    __bf16 (*rep)[2056] = (__bf16(*)[2056])smem;
    float* red = (float*)(smem + 32896);
    __bf16* attn_s = (__bf16*)(smem + 49280);

    const int bid = blockIdx.x, tid = threadIdx.x;
    const int lane = tid & 63, wid = tid >> 6;
    const int lane15 = lane & 15, quad = lane >> 4;
    const int bh = bid >> 3, b = bh / 12, h = bh % 12;
    const int m0 = (bid & 7) * 256 + wid * 64;

    // softmax of z_t row -> attn_s (attn/N, bf16)
    {
        const float* z = z_t + (size_t)bh * 2048;
        float v[8];
        float m = -1e30f;
#pragma unroll
        for (int j = 0; j < 8; ++j) { v[j] = z[tid + j * 256]; m = fmaxf(m, v[j]); }
#pragma unroll
        for (int off = 32; off; off >>= 1) m = fmaxf(m, __shfl_xor(m, off));
        if (lane == 0) red[wid] = m;
        __syncthreads();
        m = fmaxf(fmaxf(red[0], red[1]), fmaxf(red[2], red[3]));
        __syncthreads();
        float s = 0.f;
#pragma unroll
        for (int j = 0; j < 8; ++j) { v[j] = __expf(v[j] - m); s += v[j]; }
#pragma unroll
        for (int off = 32; off; off >>= 1) s += __shfl_xor(s, off);
        if (lane == 0) red[wid] = s;
        __syncthreads();
        s = red[0] + red[1] + red[2] + red[3];
        float inv = 1.f / (s * 2048.f);
#pragma unroll
        for (int j = 0; j < 8; ++j)
            attn_s[tid + j * 256] = (__bf16)(v[j] * inv);
    }
    __syncthreads();
    // build 8 shift replicas
    for (int idx = tid; idx < 8 * 2048; idx += 256) {
        int a = idx >> 11, u = idx & 2047;
        rep[a][u] = attn_s[(u + a) & 2047];
    }

    const __bf16* vsrc = VT + (size_t)h * 64 * 4096 + b * 2048;

    auto stage = [&](int kb, int buf) {
        __bf16* vt = (__bf16*)(smem + 32896 + buf * 8192);
#pragma unroll
        for (int c0 = 0; c0 < 512; c0 += 256) {
            int c = c0 + tid, dd = c >> 3, slot = c & 7;
            int k8 = slot ^ (dd & 7);
            async16(vsrc + (size_t)dd * 4096 + kb * 64 + k8 * 8, vt + c * 8);
        }
    };

    f32x4 acc[4][4] = {};
    stage(0, 0);
    for (int kb = 0; kb < 32; ++kb) {
        __syncthreads();                      // drains stage kb; rep ready too
        if (kb + 1 < 32) stage(kb + 1, (kb + 1) & 1);
        __bf16* vt = (__bf16*)(smem + 32896 + (kb & 1) * 8192);

#pragma unroll
        for (int ks = 0; ks < 2; ++ks) {
            int kloc = ks * 32 + quad * 8;
            int kglob = kb * 64 + kloc;
            bf16x8 af[4], bv[4];
#pragma unroll
            for (int mi = 0; mi < 4; ++mi) {
                int m = m0 + mi * 16 + lane15;
                int p = (kglob - m) & 2047;
                int al = p & 7;
                af[mi] = *(const bf16x8*)&rep[al][p - al];
            }
#pragma unroll
            for (int ni = 0; ni < 4; ++ni) {
                int dd = ni * 16 + lane15;
                int slot = (kloc >> 3) ^ (dd & 7);
                bv[ni] = *(const bf16x8*)&vt[dd * 64 + slot * 8];
            }
#pragma unroll
            for (int mi = 0; mi < 4; ++mi)
#pragma unroll
                for (int ni = 0; ni < 4; ++ni)
                    acc[mi][ni] = __builtin_amdgcn_mfma_f32_16x16x32_bf16(
                        af[mi], bv[ni], acc[mi][ni], 0, 0, 0);
        }
    }

#pragma unroll
    for (int mi = 0; mi < 4; ++mi)
#pragma unroll
        for (int ni = 0; ni < 4; ++ni)
#pragma unroll
            for (int r = 0; r < 4; ++r) {
                int i = m0 + mi * 16 + quad * 4 + r;
                int dd = ni * 16 + lane15;
                outp[(size_t)(b * 2048 + i) * 768 + h * 64 + dd] =
                    (__bf16)acc[mi][ni][r];
            }
}

// ---------------------------------------------------------------------------
// D5: out = out_pre @ Wp^T + bp  (f32)
// ---------------------------------------------------------------------------
__global__ __launch_bounds__(256, 2)
void k_out(const __bf16* __restrict__ out_pre, const __bf16* __restrict__ Wpb,
           const float* __restrict__ bp, float* __restrict__ out)
{
    __shared__ __attribute__((aligned(16))) char smem[32768];
    const int bid = blockIdx.x;
    gemm_phase<128, 1>(smem, out_pre, Wpb, out, bp, 768, 768, 768, 768,
                       (bid / 6) * 128, (bid % 6) * 128);
}

// ---------------------------------------------------------------------------
extern "C" void kernel_launch(void* const* d_in, const int* in_sizes, int n_in,
                              void* d_out, int out_size, void* d_ws, size_t ws_size,
                              hipStream_t stream)
{
    (void)in_sizes; (void)n_in; (void)out_size; (void)ws_size;
    const float* x  = (const float*)d_in[0];
    const float* Wq = (const float*)d_in[1];
    const float* Wk = (const float*)d_in[2];
    const float* Wv = (const float*)d_in[3];
    const float* Wp = (const float*)d_in[4];
    const float* bp = (const float*)d_in[5];

    char* w = (char*)d_ws;
    auto alloc = [&](size_t bytes) {
        char* p = w; w += (bytes + 255) & ~(size_t)255; return p;
    };
    float*  x_avg   = (float*) alloc((size_t)2 * 768 * 4);
    __bf16* xb      = (__bf16*)alloc((size_t)4096 * 768 * 2);
    __bf16* Wvb     = (__bf16*)alloc((size_t)768 * 768 * 2);
    __bf16* Wpb     = (__bf16*)alloc((size_t)768 * 768 * 2);
    __bf16* Ub      = (__bf16*)alloc((size_t)64 * 768 * 2);
    float*  z_t     = (float*) alloc((size_t)24 * 2048 * 4);
    __bf16* VT      = (__bf16*)alloc((size_t)768 * 4096 * 2);
    __bf16* out_pre = (__bf16*)alloc((size_t)4096 * 768 * 2);

    hipMemsetAsync(x_avg, 0, 2 * 768 * sizeof(float), stream);
    k_prep <<<512, 256, 0, stream>>>(x, Wv, Wp, xb, Wvb, Wpb, x_avg);
    k_ub   <<<24,  256, 0, stream>>>(x_avg, Wk, Wq, Ub);
    k_gemms<<<224, 256, 0, stream>>>(xb, Wvb, Ub, VT, z_t);
    k_conv <<<192, 256, 0, stream>>>(z_t, VT, out_pre);
    k_out  <<<192, 256, 0, stream>>>(out_pre, Wpb, bp, (float*)d_out);
}

// Round 7
// 159.744 us; speedup vs baseline: 1.0620x; 1.0620x over previous
//
#include <hip/hip_runtime.h>

// ---------------------------------------------------------------------------
// AveragedKeyCircularConvolutionalAttention  (B=2, N=2048, C=768, h=12, d=64)
// R7: halve K-loop iteration counts (BK=64 GEMMs, K-chunk=128 conv).
// Theory: at ~1 block/CU each iter pays a full barrier+vmcnt(0) drain
// (~600-900cyc, cross-XCD L2); cost ~ #iters, so halve #iters.
//
//  D0 memset : x_avg[2][768] = 0
//  D1 k_prep : x,Wv,Wp -> bf16 ; slab colsum -> atomicAdd x_avg  (512 blk)
//  D2 k_ub   : Ub = SCALE/2048 * (x_avg@Wk^T) @ Wq rows          (24 blk)
//  D3 k_gemms: VT = (x@Wv^T)^T (192) || z_t = (xb@Ub^T)^T (32)   (224 blk)
//  D4 k_conv : in-block softmax(z_t) + circulant MFMA -> out_pre (384 blk)
//  D5 k_out  : out = out_pre @ Wp^T + bp  (f32)                  (192 blk)
// ---------------------------------------------------------------------------

typedef __bf16 bf16x8 __attribute__((ext_vector_type(8)));
typedef float  f32x4  __attribute__((ext_vector_type(4)));

#define AS_GLOBAL(p) ((const __attribute__((address_space(1))) unsigned int*)(p))
#define AS_LDS(p)    ((__attribute__((address_space(3))) unsigned int*)(p))

__device__ __forceinline__ void async16(const void* g, void* l) {
    __builtin_amdgcn_global_load_lds(AS_GLOBAL(g), AS_LDS(l), 16, 0, 0);
}

struct bf4 { __bf16 a, b, c, d; };

// ---------------------------------------------------------------------------
// bf16 GEMM tile:  C[m][n] = sum_k A[m][k]*Bt[n][k].  BK=64, dbuf.
// Rows stored as 8 chunks of 16B; chunk slot = k8 ^ (row&7)  (2-way max).
// MODE 0: bf16 store   MODE 1: f32 + bias   MODE 2: z transposed f32
// ---------------------------------------------------------------------------
template <int BM, int BN, int MODE>
__device__ void gemm_phase(char* smem, const __bf16* __restrict__ A,
                           const __bf16* __restrict__ Bt, void* __restrict__ Cout,
                           const float* __restrict__ bias,
                           int K, int ldA, int ldBt, int ldC, int mBase, int nBase)
{
    constexpr int BK = 64;
    constexpr int STRIDE = (BM + BN) * BK * 2;   // bytes per buffer
    constexpr int WM = BM / 2, WN = BN / 2;
    constexpr int MI = WM / 16, NI = WN / 16;
    const int tid = threadIdx.x;
    const int lane = tid & 63, wid = tid >> 6;
    const int lane15 = lane & 15, quad = lane >> 4;
    const int wm = (wid & 1) * WM, wn = (wid >> 1) * WN;

    auto stage = [&](int kb, int buf) {
        __bf16* As = (__bf16*)(smem + buf * STRIDE);
        __bf16* Bs = As + BM * BK;
#pragma unroll
        for (int c0 = 0; c0 < BM * 8; c0 += 256) {
            int c = c0 + tid, row = c >> 3, slot = c & 7;
            int k8 = slot ^ (row & 7);
            async16(A + (size_t)(mBase + row) * ldA + kb + k8 * 8, As + c * 8);
        }
#pragma unroll
        for (int c0 = 0; c0 < BN * 8; c0 += 256) {
            int c = c0 + tid, row = c >> 3, slot = c & 7;
            int k8 = slot ^ (row & 7);
            async16(Bt + (size_t)(nBase + row) * ldBt + kb + k8 * 8, Bs + c * 8);
        }
    };

    f32x4 acc[MI][NI] = {};
    const int nk = K >> 6;

    stage(0, 0);
    for (int ki = 0; ki < nk; ++ki) {
        __syncthreads();                       // drains stage ki
        if (ki + 1 < nk) stage((ki + 1) << 6, (ki + 1) & 1);

        __bf16* As = (__bf16*)(smem + (ki & 1) * STRIDE);
        __bf16* Bs = As + BM * BK;
#pragma unroll
        for (int ks = 0; ks < 2; ++ks) {
            bf16x8 af[MI], bv[NI];
#pragma unroll
            for (int mi = 0; mi < MI; ++mi) {
                int row = wm + mi * 16 + lane15;
                af[mi] = *(const bf16x8*)&As[row * 64 + ((ks * 4 + quad) ^ (row & 7)) * 8];
            }
#pragma unroll
            for (int ni = 0; ni < NI; ++ni) {
                int row = wn + ni * 16 + lane15;
                bv[ni] = *(const bf16x8*)&Bs[row * 64 + ((ks * 4 + quad) ^ (row & 7)) * 8];
            }
#pragma unroll
            for (int mi = 0; mi < MI; ++mi)
#pragma unroll
                for (int ni = 0; ni < NI; ++ni)
                    acc[mi][ni] = __builtin_amdgcn_mfma_f32_16x16x32_bf16(
                        af[mi], bv[ni], acc[mi][ni], 0, 0, 0);
        }
    }

#pragma unroll
    for (int mi = 0; mi < MI; ++mi)
#pragma unroll
        for (int ni = 0; ni < NI; ++ni)
#pragma unroll
            for (int r = 0; r < 4; ++r) {
                int row = mBase + wm + mi * 16 + quad * 4 + r;
                int col = nBase + wn + ni * 16 + lane15;
                float v = acc[mi][ni][r];
                if (MODE == 0) {
                    ((__bf16*)Cout)[(size_t)row * ldC + col] = (__bf16)v;
                } else if (MODE == 1) {
                    ((float*)Cout)[(size_t)row * ldC + col] = v + bias[col];
                } else {
                    int b = row >> 11;
                    if ((unsigned)(col - b * 12) < 12u)
                        ((float*)Cout)[(size_t)col * 2048 + (row & 2047)] = v;
                }
            }
}

// ---------------------------------------------------------------------------
// D1: converts + slab colsum (block owns 8 contiguous rows of x)
// ---------------------------------------------------------------------------
__global__ __launch_bounds__(256)
void k_prep(const float* __restrict__ x, const float* __restrict__ Wv,
            const float* __restrict__ Wp,
            __bf16* __restrict__ xb, __bf16* __restrict__ Wvb,
            __bf16* __restrict__ Wpb, float* __restrict__ x_avg)
{
    const int bid = blockIdx.x, tid = threadIdx.x;
    __shared__ float sums[768];
    for (int c = tid; c < 768; c += 256) sums[c] = 0.f;
    __syncthreads();

    const float4* xs = (const float4*)x + (size_t)bid * 1536;  // 8 rows
    bf4* xd = (bf4*)xb + (size_t)bid * 1536;
#pragma unroll
    for (int r = 0; r < 6; ++r) {
        int j = tid + r * 256;          // < 1536
        float4 v = xs[j];
        xd[j] = bf4{(__bf16)v.x, (__bf16)v.y, (__bf16)v.z, (__bf16)v.w};
        int col = (j % 192) * 4;
        atomicAdd(&sums[col + 0], v.x);
        atomicAdd(&sums[col + 1], v.y);
        atomicAdd(&sums[col + 2], v.z);
        atomicAdd(&sums[col + 3], v.w);
    }
    const float4* wv4 = (const float4*)Wv;  bf4* wvb4 = (bf4*)Wvb;
    const float4* wp4 = (const float4*)Wp;  bf4* wpb4 = (bf4*)Wpb;
    for (int t = tid; t < 288; t += 256) {
        int g = bid * 288 + t;
        float4 v = wv4[g];
        wvb4[g] = bf4{(__bf16)v.x, (__bf16)v.y, (__bf16)v.z, (__bf16)v.w};
        float4 w2 = wp4[g];
        wpb4[g] = bf4{(__bf16)w2.x, (__bf16)w2.y, (__bf16)w2.z, (__bf16)w2.w};
    }
    __syncthreads();
    const int b = bid >> 8;
    for (int c = tid; c < 768; c += 256)
        atomicAdd(&x_avg[b * 768 + c], sums[c]);
}

// ---------------------------------------------------------------------------
// D2: Ub rows, one block per bh (24).  Coalesced wave-per-row K_avg.
// ---------------------------------------------------------------------------
__global__ __launch_bounds__(256)
void k_ub(const float* __restrict__ x_avg, const float* __restrict__ Wk,
          const float* __restrict__ Wq, __bf16* __restrict__ Ub)
{
    const int bid = blockIdx.x, tid = threadIdx.x;
    const int lane = tid & 63, wid = tid >> 6;
    __shared__ float sx[768];
    __shared__ float sk[64];
    int b = bid / 12, h = bid % 12;
    for (int c = tid; c < 768; c += 256) sx[c] = x_avg[b * 768 + c];
    __syncthreads();
    for (int round = 0; round < 16; ++round) {
        int o = round * 4 + wid;
        const float* wk = Wk + (size_t)(h * 64 + o) * 768;
        float s = 0.f;
#pragma unroll
        for (int cc0 = 0; cc0 < 768; cc0 += 64) s += sx[cc0 + lane] * wk[cc0 + lane];
#pragma unroll
        for (int off = 32; off; off >>= 1) s += __shfl_down(s, off);
        if (lane == 0) sk[o] = s * (0.125f / 2048.f);   // fold SCALE and 1/N
    }
    __syncthreads();
    for (int c = tid; c < 768; c += 256) {
        float s = 0.f;
#pragma unroll 16
        for (int d2 = 0; d2 < 64; ++d2)
            s += sk[d2] * Wq[(size_t)(h * 64 + d2) * 768 + c];
        Ub[(size_t)bid * 768 + c] = (__bf16)s;
    }
}

// ---------------------------------------------------------------------------
// D3: VT gemm (blocks 0..191)  ||  z gemm (blocks 192..223)
// Ub rows 24..63 hold ws poison (finite bf16); z_t cols >=24 discarded by
// the MODE-2 bound check.
// ---------------------------------------------------------------------------
__global__ __launch_bounds__(256, 2)
void k_gemms(const __bf16* __restrict__ xb, const __bf16* __restrict__ Wvb,
             const __bf16* __restrict__ Ub, __bf16* __restrict__ VT,
             float* __restrict__ z_t)
{
    __shared__ __attribute__((aligned(16))) char smem[65536];
    const int bid = blockIdx.x;
    if (bid < 192) {
        gemm_phase<128, 128, 0>(smem, Wvb, xb, VT, nullptr, 768, 768, 768, 4096,
                                (bid / 32) * 128, (bid % 32) * 128);
    } else {
        gemm_phase<128, 64, 2>(smem, xb, Ub, z_t, nullptr, 768, 768, 768, 0,
                               (bid - 192) * 128, 0);
    }
}

// ---------------------------------------------------------------------------
// D4: conv, 384 blocks: 16 tiles of 128 rows x 64 dd per (b,h).
// K-chunk 128 (16 iters), dbuf V-tile 64x128.
// smem: rep[8][2056] @0 (32896) | vt0 @32896 (16384, aliases red) |
//       vt1 @49280 (16384) | attn_s @65664 (4096)   total 69760
// ---------------------------------------------------------------------------
__global__ __launch_bounds__(256, 2)
void k_conv(const float* __restrict__ z_t, const __bf16* __restrict__ VT,
            __bf16* __restrict__ outp)
{
    __shared__ __attribute__((aligned(16))) char smem[69760];
    __bf16 (*rep)[2056] = (__bf16(*)[2056])smem;
    float* red = (float*)(smem + 32896);
    __bf16* attn_s = (__bf16*)(smem + 65664);

    const int bid = blockIdx.x, tid = threadIdx.x;
    const int lane = tid & 63, wid = tid >> 6;
    const int lane15 = lane & 15, quad = lane >> 4;
    const int bh = bid >> 4, b = bh / 12, h = bh % 12;
    const int m0 = (bid & 15) * 128 + (wid & 1) * 64;
    const int wn = (wid >> 1) * 32;

    // softmax of z_t row -> attn_s (attn/N, bf16); red aliases vt0 (pre-stage)
    {
        const float* z = z_t + (size_t)bh * 2048;
        float v[8];
        float m = -1e30f;
#pragma unroll
        for (int j = 0; j < 8; ++j) { v[j] = z[tid + j * 256]; m = fmaxf(m, v[j]); }
#pragma unroll
        for (int off = 32; off; off >>= 1) m = fmaxf(m, __shfl_xor(m, off));
        if (lane == 0) red[wid] = m;
        __syncthreads();
        m = fmaxf(fmaxf(red[0], red[1]), fmaxf(red[2], red[3]));
        __syncthreads();
        float s = 0.f;
#pragma unroll
        for (int j = 0; j < 8; ++j) { v[j] = __expf(v[j] - m); s += v[j]; }
#pragma unroll
        for (int off = 32; off; off >>= 1) s += __shfl_xor(s, off);
        if (lane == 0) red[wid] = s;
        __syncthreads();
        s = red[0] + red[1] + red[2] + red[3];
        float inv = 1.f / (s * 2048.f);
#pragma unroll
        for (int j = 0; j < 8; ++j)
            attn_s[tid + j * 256] = (__bf16)(v[j] * inv);
    }
    __syncthreads();
    for (int idx = tid; idx < 8 * 2048; idx += 256) {
        int a = idx >> 11, u = idx & 2047;
        rep[a][u] = attn_s[(u + a) & 2047];
    }

    const __bf16* vsrc = VT + (size_t)h * 64 * 4096 + b * 2048;

    // vt tile: 64 dd rows x 128 k, rows as 16 chunks of 16B, slot = k8^(dd&15)
    auto stage = [&](int kb, int buf) {
        __bf16* vt = (__bf16*)(smem + 32896 + buf * 16384);
#pragma unroll
        for (int c0 = 0; c0 < 1024; c0 += 256) {
            int c = c0 + tid, dd = c >> 4, slot = c & 15;
            int k8 = slot ^ (dd & 15);
            async16(vsrc + (size_t)dd * 4096 + kb * 128 + k8 * 8, vt + c * 8);
        }
    };

    f32x4 acc[4][2] = {};
    stage(0, 0);
    for (int kb = 0; kb < 16; ++kb) {
        __syncthreads();                      // drains stage kb; rep ready too
        if (kb + 1 < 16) stage(kb + 1, (kb + 1) & 1);
        __bf16* vt = (__bf16*)(smem + 32896 + (kb & 1) * 16384);

#pragma unroll
        for (int ks = 0; ks < 4; ++ks) {
            int kloc = ks * 32 + quad * 8;
            int kglob = kb * 128 + kloc;
            bf16x8 af[4], bv[2];
#pragma unroll
            for (int mi = 0; mi < 4; ++mi) {
                int m = m0 + mi * 16 + lane15;
                int p = (kglob - m) & 2047;
                int al = p & 7;
                af[mi] = *(const bf16x8*)&rep[al][p - al];
            }
#pragma unroll
            for (int ni = 0; ni < 2; ++ni) {
                int dd = wn + ni * 16 + lane15;
                int slot = (ks * 4 + quad) ^ (dd & 15);
                bv[ni] = *(const bf16x8*)&vt[dd * 128 + slot * 8];
            }
#pragma unroll
            for (int mi = 0; mi < 4; ++mi)
#pragma unroll
                for (int ni = 0; ni < 2; ++ni)
                    acc[mi][ni] = __builtin_amdgcn_mfma_f32_16x16x32_bf16(
                        af[mi], bv[ni], acc[mi][ni], 0, 0, 0);
        }
    }

#pragma unroll
    for (int mi = 0; mi < 4; ++mi)
#pragma unroll
        for (int ni = 0; ni < 2; ++ni)
#pragma unroll
            for (int r = 0; r < 4; ++r) {
                int i = m0 + mi * 16 + quad * 4 + r;
                int dd = wn + ni * 16 + lane15;
                outp[(size_t)(b * 2048 + i) * 768 + h * 64 + dd] =
                    (__bf16)acc[mi][ni][r];
            }
}

// ---------------------------------------------------------------------------
// D5: out = out_pre @ Wp^T + bp  (f32)
// ---------------------------------------------------------------------------
__global__ __launch_bounds__(256, 2)
void k_out(const __bf16* __restrict__ out_pre, const __bf16* __restrict__ Wpb,
           const float* __restrict__ bp, float* __restrict__ out)
{
    __shared__ __attribute__((aligned(16))) char smem[65536];
    const int bid = blockIdx.x;
    gemm_phase<128, 128, 1>(smem, out_pre, Wpb, out, bp, 768, 768, 768, 768,
                            (bid / 6) * 128, (bid % 6) * 128);
}

// ---------------------------------------------------------------------------
extern "C" void kernel_launch(void* const* d_in, const int* in_sizes, int n_in,
                              void* d_out, int out_size, void* d_ws, size_t ws_size,
                              hipStream_t stream)
{
    (void)in_sizes; (void)n_in; (void)out_size; (void)ws_size;
    const float* x  = (const float*)d_in[0];
    const float* Wq = (const float*)d_in[1];
    const float* Wk = (const float*)d_in[2];
    const float* Wv = (const float*)d_in[3];
    const float* Wp = (const float*)d_in[4];
    const float* bp = (const float*)d_in[5];

    char* w = (char*)d_ws;
    auto alloc = [&](size_t bytes) {
        char* p = w; w += (bytes + 255) & ~(size_t)255; return p;
    };
    float*  x_avg   = (float*) alloc((size_t)2 * 768 * 4);
    __bf16* xb      = (__bf16*)alloc((size_t)4096 * 768 * 2);
    __bf16* Wvb     = (__bf16*)alloc((size_t)768 * 768 * 2);
    __bf16* Wpb     = (__bf16*)alloc((size_t)768 * 768 * 2);
    __bf16* Ub      = (__bf16*)alloc((size_t)64 * 768 * 2);
    float*  z_t     = (float*) alloc((size_t)24 * 2048 * 4);
    __bf16* VT      = (__bf16*)alloc((size_t)768 * 4096 * 2);
    __bf16* out_pre = (__bf16*)alloc((size_t)4096 * 768 * 2);

    hipMemsetAsync(x_avg, 0, 2 * 768 * sizeof(float), stream);
    k_prep <<<512, 256, 0, stream>>>(x, Wv, Wp, xb, Wvb, Wpb, x_avg);
    k_ub   <<<24,  256, 0, stream>>>(x_avg, Wk, Wq, Ub);
    k_gemms<<<224, 256, 0, stream>>>(xb, Wvb, Ub, VT, z_t);
    k_conv <<<384, 256, 0, stream>>>(z_t, VT, out_pre);
    k_out  <<<192, 256, 0, stream>>>(out_pre, Wpb, bp, (float*)d_out);
}

// Round 8
// 157.626 us; speedup vs baseline: 1.0763x; 1.0134x over previous
//
#include <hip/hip_runtime.h>

// ---------------------------------------------------------------------------
// AveragedKeyCircularConvolutionalAttention  (B=2, N=2048, C=768, h=12, d=64)
// R8: 4-node pipeline (was 6). No memset, no atomics.
//
//  N1 k_prep : x,Wv,Wp -> bf16 ; blocks 0..63 write colsum partials x_part
//  N2 k_mid  : blocks 0..191  VT = (x@Wv^T)^T  (BK=64 dbuf MFMA)
//              blocks 192..287 ubz: x_avg -> K_avg -> u (fp32) -> z_t (VALU)
//  N3 k_conv : in-block softmax(z_t) + circulant MFMA -> out_pre (384 blk)
//  N4 k_out  : out = out_pre @ Wp^T + bp  (f32)                  (192 blk)
// ---------------------------------------------------------------------------

typedef __bf16 bf16x8 __attribute__((ext_vector_type(8)));
typedef float  f32x4  __attribute__((ext_vector_type(4)));

#define AS_GLOBAL(p) ((const __attribute__((address_space(1))) unsigned int*)(p))
#define AS_LDS(p)    ((__attribute__((address_space(3))) unsigned int*)(p))

__device__ __forceinline__ void async16(const void* g, void* l) {
    __builtin_amdgcn_global_load_lds(AS_GLOBAL(g), AS_LDS(l), 16, 0, 0);
}

struct bf4 { __bf16 a, b, c, d; };

// ---------------------------------------------------------------------------
// bf16 GEMM tile:  C[m][n] = sum_k A[m][k]*Bt[n][k].  BK=64, dbuf.
// Rows stored as 8 chunks of 16B; chunk slot = k8 ^ (row&7)  (2-way max).
// MODE 0: bf16 store   MODE 1: f32 + bias
// ---------------------------------------------------------------------------
template <int BM, int BN, int MODE>
__device__ void gemm_phase(char* smem, const __bf16* __restrict__ A,
                           const __bf16* __restrict__ Bt, void* __restrict__ Cout,
                           const float* __restrict__ bias,
                           int K, int ldA, int ldBt, int ldC, int mBase, int nBase)
{
    constexpr int BK = 64;
    constexpr int STRIDE = (BM + BN) * BK * 2;   // bytes per buffer
    constexpr int WM = BM / 2, WN = BN / 2;
    constexpr int MI = WM / 16, NI = WN / 16;
    const int tid = threadIdx.x;
    const int lane = tid & 63, wid = tid >> 6;
    const int lane15 = lane & 15, quad = lane >> 4;
    const int wm = (wid & 1) * WM, wn = (wid >> 1) * WN;

    auto stage = [&](int kb, int buf) {
        __bf16* As = (__bf16*)(smem + buf * STRIDE);
        __bf16* Bs = As + BM * BK;
#pragma unroll
        for (int c0 = 0; c0 < BM * 8; c0 += 256) {
            int c = c0 + tid, row = c >> 3, slot = c & 7;
            int k8 = slot ^ (row & 7);
            async16(A + (size_t)(mBase + row) * ldA + kb + k8 * 8, As + c * 8);
        }
#pragma unroll
        for (int c0 = 0; c0 < BN * 8; c0 += 256) {
            int c = c0 + tid, row = c >> 3, slot = c & 7;
            int k8 = slot ^ (row & 7);
            async16(Bt + (size_t)(nBase + row) * ldBt + kb + k8 * 8, Bs + c * 8);
        }
    };

    f32x4 acc[MI][NI] = {};
    const int nk = K >> 6;

    stage(0, 0);
    for (int ki = 0; ki < nk; ++ki) {
        __syncthreads();                       // drains stage ki
        if (ki + 1 < nk) stage((ki + 1) << 6, (ki + 1) & 1);

        __bf16* As = (__bf16*)(smem + (ki & 1) * STRIDE);
        __bf16* Bs = As + BM * BK;
#pragma unroll
        for (int ks = 0; ks < 2; ++ks) {
            bf16x8 af[MI], bv[NI];
#pragma unroll
            for (int mi = 0; mi < MI; ++mi) {
                int row = wm + mi * 16 + lane15;
                af[mi] = *(const bf16x8*)&As[row * 64 + ((ks * 4 + quad) ^ (row & 7)) * 8];
            }
#pragma unroll
            for (int ni = 0; ni < NI; ++ni) {
                int row = wn + ni * 16 + lane15;
                bv[ni] = *(const bf16x8*)&Bs[row * 64 + ((ks * 4 + quad) ^ (row & 7)) * 8];
            }
#pragma unroll
            for (int mi = 0; mi < MI; ++mi)
#pragma unroll
                for (int ni = 0; ni < NI; ++ni)
                    acc[mi][ni] = __builtin_amdgcn_mfma_f32_16x16x32_bf16(
                        af[mi], bv[ni], acc[mi][ni], 0, 0, 0);
        }
    }

#pragma unroll
    for (int mi = 0; mi < MI; ++mi)
#pragma unroll
        for (int ni = 0; ni < NI; ++ni)
#pragma unroll
            for (int r = 0; r < 4; ++r) {
                int row = mBase + wm + mi * 16 + quad * 4 + r;
                int col = nBase + wn + ni * 16 + lane15;
                float v = acc[mi][ni][r];
                if (MODE == 0) {
                    ((__bf16*)Cout)[(size_t)row * ldC + col] = (__bf16)v;
                } else {
                    ((float*)Cout)[(size_t)row * ldC + col] = v + bias[col];
                }
            }
}

// ---------------------------------------------------------------------------
// N1: converts; blocks 0..63 also write column-sum partials over 64-row
// groups: x_part[g][c] = sum_{r in [g*64,g*64+64)} x[r][c]   (no atomics)
// ---------------------------------------------------------------------------
__global__ __launch_bounds__(256)
void k_prep(const float* __restrict__ x, const float* __restrict__ Wv,
            const float* __restrict__ Wp,
            __bf16* __restrict__ xb, __bf16* __restrict__ Wvb,
            __bf16* __restrict__ Wpb, float* __restrict__ x_part)
{
    const int bid = blockIdx.x, tid = threadIdx.x;

    const float4* xs = (const float4*)x + (size_t)bid * 1536;  // 8 rows
    bf4* xd = (bf4*)xb + (size_t)bid * 1536;
#pragma unroll
    for (int r = 0; r < 6; ++r) {
        int j = tid + r * 256;          // < 1536
        float4 v = xs[j];
        xd[j] = bf4{(__bf16)v.x, (__bf16)v.y, (__bf16)v.z, (__bf16)v.w};
    }
    const float4* wv4 = (const float4*)Wv;  bf4* wvb4 = (bf4*)Wvb;
    const float4* wp4 = (const float4*)Wp;  bf4* wpb4 = (bf4*)Wpb;
    for (int t = tid; t < 288; t += 256) {
        int g = bid * 288 + t;
        float4 v = wv4[g];
        wvb4[g] = bf4{(__bf16)v.x, (__bf16)v.y, (__bf16)v.z, (__bf16)v.w};
        float4 w2 = wp4[g];
        wpb4[g] = bf4{(__bf16)w2.x, (__bf16)w2.y, (__bf16)w2.z, (__bf16)w2.w};
    }

    if (bid < 64) {  // colsum of rows [bid*64, bid*64+64)
        const float* base = x + (size_t)bid * 64 * 768;
        float s0 = 0.f, s1 = 0.f, s2 = 0.f;
        for (int r = 0; r < 64; ++r) {
            const float* row = base + r * 768;
            s0 += row[tid];
            s1 += row[tid + 256];
            s2 += row[tid + 512];
        }
        x_part[bid * 768 + tid]       = s0;
        x_part[bid * 768 + tid + 256] = s1;
        x_part[bid * 768 + tid + 512] = s2;
    }
}

// ---------------------------------------------------------------------------
// N2: blocks 0..191 VT gemm;  blocks 192..287 ubz (4 blocks per bh,
// each handling a 512-token quarter):
//   x_avg (from x_part) -> K_avg (h-slice) -> u row (fp32) -> z_t quarter
// ---------------------------------------------------------------------------
__global__ __launch_bounds__(256, 2)
void k_mid(const __bf16* __restrict__ xb, const __bf16* __restrict__ Wvb,
           const float* __restrict__ x_part, const float* __restrict__ Wk,
           const float* __restrict__ Wq,
           __bf16* __restrict__ VT, float* __restrict__ z_t)
{
    __shared__ __attribute__((aligned(16))) char smem[65536];
    const int bid = blockIdx.x;
    if (bid < 192) {
        gemm_phase<128, 128, 0>(smem, Wvb, xb, VT, nullptr, 768, 768, 768, 4096,
                                (bid / 32) * 128, (bid % 32) * 128);
        return;
    }
    const int tid = threadIdx.x;
    const int lane = tid & 63, wid = tid >> 6;
    const int idx = bid - 192;                 // 0..95
    const int bh = idx >> 2, q = idx & 3;
    const int b = bh / 12, h = bh % 12;
    float* xa  = (float*)smem;                 // 768
    float* uld = xa + 768;                     // 768
    float* ka  = uld + 768;                    // 64

    for (int c = tid; c < 768; c += 256) {
        float s = 0.f;
#pragma unroll
        for (int g = 0; g < 32; ++g) s += x_part[(b * 32 + g) * 768 + c];
        xa[c] = s;
    }
    __syncthreads();
    for (int round = 0; round < 16; ++round) {  // K_avg, wave-per-row
        int o = round * 4 + wid;
        const float* wk = Wk + (size_t)(h * 64 + o) * 768;
        float s = 0.f;
#pragma unroll
        for (int c0 = 0; c0 < 768; c0 += 64) s += xa[c0 + lane] * wk[c0 + lane];
#pragma unroll
        for (int off = 32; off; off >>= 1) s += __shfl_down(s, off);
        if (lane == 0) ka[o] = s * (0.125f / 2048.f);  // fold SCALE and 1/N
    }
    __syncthreads();
    for (int c = tid; c < 768; c += 256) {      // u row (fp32)
        float s = 0.f;
#pragma unroll 16
        for (int d = 0; d < 64; ++d)
            s += ka[d] * Wq[(size_t)(h * 64 + d) * 768 + c];
        uld[c] = s;
    }
    __syncthreads();
    // z for tokens q*512 + tid and + 256
    const int t0 = q * 512 + tid, t1 = t0 + 256;
    const bf16x8* r0 = (const bf16x8*)(xb + (size_t)(b * 2048 + t0) * 768);
    const bf16x8* r1 = (const bf16x8*)(xb + (size_t)(b * 2048 + t1) * 768);
    const float4* u4 = (const float4*)uld;
    float s0 = 0.f, s1 = 0.f;
#pragma unroll 8
    for (int j = 0; j < 96; ++j) {
        bf16x8 v0 = r0[j], v1 = r1[j];
        float4 ua = u4[j * 2], ub = u4[j * 2 + 1];
        s0 += (float)v0[0] * ua.x + (float)v0[1] * ua.y + (float)v0[2] * ua.z
            + (float)v0[3] * ua.w + (float)v0[4] * ub.x + (float)v0[5] * ub.y
            + (float)v0[6] * ub.z + (float)v0[7] * ub.w;
        s1 += (float)v1[0] * ua.x + (float)v1[1] * ua.y + (float)v1[2] * ua.z
            + (float)v1[3] * ua.w + (float)v1[4] * ub.x + (float)v1[5] * ub.y
            + (float)v1[6] * ub.z + (float)v1[7] * ub.w;
    }
    z_t[(size_t)bh * 2048 + t0] = s0;
    z_t[(size_t)bh * 2048 + t1] = s1;
}

// ---------------------------------------------------------------------------
// N3: conv, 384 blocks: 16 tiles of 128 rows x 64 dd per (b,h).
// K-chunk 128 (16 iters), dbuf V-tile 64x128.
// smem: rep[8][2056] @0 (32896) | vt0 @32896 (16384, aliases red) |
//       vt1 @49280 (16384) | attn_s @65664 (4096)   total 69760
// ---------------------------------------------------------------------------
__global__ __launch_bounds__(256, 2)
void k_conv(const float* __restrict__ z_t, const __bf16* __restrict__ VT,
            __bf16* __restrict__ outp)
{
    __shared__ __attribute__((aligned(16))) char smem[69760];
    __bf16 (*rep)[2056] = (__bf16(*)[2056])smem;
    float* red = (float*)(smem + 32896);
    __bf16* attn_s = (__bf16*)(smem + 65664);

    const int bid = blockIdx.x, tid = threadIdx.x;
    const int lane = tid & 63, wid = tid >> 6;
    const int lane15 = lane & 15, quad = lane >> 4;
    const int bh = bid >> 4, b = bh / 12, h = bh % 12;
    const int m0 = (bid & 15) * 128 + (wid & 1) * 64;
    const int wn = (wid >> 1) * 32;

    // softmax of z_t row -> attn_s (attn/N, bf16)
    {
        const float* z = z_t + (size_t)bh * 2048;
        float v[8];
        float m = -1e30f;
#pragma unroll
        for (int j = 0; j < 8; ++j) { v[j] = z[tid + j * 256]; m = fmaxf(m, v[j]); }
#pragma unroll
        for (int off = 32; off; off >>= 1) m = fmaxf(m, __shfl_xor(m, off));
        if (lane == 0) red[wid] = m;
        __syncthreads();
        m = fmaxf(fmaxf(red[0], red[1]), fmaxf(red[2], red[3]));
        __syncthreads();
        float s = 0.f;
#pragma unroll
        for (int j = 0; j < 8; ++j) { v[j] = __expf(v[j] - m); s += v[j]; }
#pragma unroll
        for (int off = 32; off; off >>= 1) s += __shfl_xor(s, off);
        if (lane == 0) red[wid] = s;
        __syncthreads();
        s = red[0] + red[1] + red[2] + red[3];
        float inv = 1.f / (s * 2048.f);
#pragma unroll
        for (int j = 0; j < 8; ++j)
            attn_s[tid + j * 256] = (__bf16)(v[j] * inv);
    }
    __syncthreads();
    for (int idx = tid; idx < 8 * 2048; idx += 256) {
        int a = idx >> 11, u = idx & 2047;
        rep[a][u] = attn_s[(u + a) & 2047];
    }

    const __bf16* vsrc = VT + (size_t)h * 64 * 4096 + b * 2048;

    auto stage = [&](int kb, int buf) {
        __bf16* vt = (__bf16*)(smem + 32896 + buf * 16384);
#pragma unroll
        for (int c0 = 0; c0 < 1024; c0 += 256) {
            int c = c0 + tid, dd = c >> 4, slot = c & 15;
            int k8 = slot ^ (dd & 15);
            async16(vsrc + (size_t)dd * 4096 + kb * 128 + k8 * 8, vt + c * 8);
        }
    };

    f32x4 acc[4][2] = {};
    stage(0, 0);
    for (int kb = 0; kb < 16; ++kb) {
        __syncthreads();                      // drains stage kb; rep ready too
        if (kb + 1 < 16) stage(kb + 1, (kb + 1) & 1);
        __bf16* vt = (__bf16*)(smem + 32896 + (kb & 1) * 16384);

#pragma unroll
        for (int ks = 0; ks < 4; ++ks) {
            int kloc = ks * 32 + quad * 8;
            int kglob = kb * 128 + kloc;
            bf16x8 af[4], bv[2];
#pragma unroll
            for (int mi = 0; mi < 4; ++mi) {
                int m = m0 + mi * 16 + lane15;
                int p = (kglob - m) & 2047;
                int al = p & 7;
                af[mi] = *(const bf16x8*)&rep[al][p - al];
            }
#pragma unroll
            for (int ni = 0; ni < 2; ++ni) {
                int dd = wn + ni * 16 + lane15;
                int slot = (ks * 4 + quad) ^ (dd & 15);
                bv[ni] = *(const bf16x8*)&vt[dd * 128 + slot * 8];
            }
#pragma unroll
            for (int mi = 0; mi < 4; ++mi)
#pragma unroll
                for (int ni = 0; ni < 2; ++ni)
                    acc[mi][ni] = __builtin_amdgcn_mfma_f32_16x16x32_bf16(
                        af[mi], bv[ni], acc[mi][ni], 0, 0, 0);
        }
    }

#pragma unroll
    for (int mi = 0; mi < 4; ++mi)
#pragma unroll
        for (int ni = 0; ni < 2; ++ni)
#pragma unroll
            for (int r = 0; r < 4; ++r) {
                int i = m0 + mi * 16 + quad * 4 + r;
                int dd = wn + ni * 16 + lane15;
                outp[(size_t)(b * 2048 + i) * 768 + h * 64 + dd] =
                    (__bf16)acc[mi][ni][r];
            }
}

// ---------------------------------------------------------------------------
// N4: out = out_pre @ Wp^T + bp  (f32)
// ---------------------------------------------------------------------------
__global__ __launch_bounds__(256, 2)
void k_out(const __bf16* __restrict__ out_pre, const __bf16* __restrict__ Wpb,
           const float* __restrict__ bp, float* __restrict__ out)
{
    __shared__ __attribute__((aligned(16))) char smem[65536];
    const int bid = blockIdx.x;
    gemm_phase<128, 128, 1>(smem, out_pre, Wpb, out, bp, 768, 768, 768, 768,
                            (bid / 6) * 128, (bid % 6) * 128);
}

// ---------------------------------------------------------------------------
extern "C" void kernel_launch(void* const* d_in, const int* in_sizes, int n_in,
                              void* d_out, int out_size, void* d_ws, size_t ws_size,
                              hipStream_t stream)
{
    (void)in_sizes; (void)n_in; (void)out_size; (void)ws_size;
    const float* x  = (const float*)d_in[0];
    const float* Wq = (const float*)d_in[1];
    const float* Wk = (const float*)d_in[2];
    const float* Wv = (const float*)d_in[3];
    const float* Wp = (const float*)d_in[4];
    const float* bp = (const float*)d_in[5];

    char* w = (char*)d_ws;
    auto alloc = [&](size_t bytes) {
        char* p = w; w += (bytes + 255) & ~(size_t)255; return p;
    };
    float*  x_part  = (float*) alloc((size_t)64 * 768 * 4);
    __bf16* xb      = (__bf16*)alloc((size_t)4096 * 768 * 2);
    __bf16* Wvb     = (__bf16*)alloc((size_t)768 * 768 * 2);
    __bf16* Wpb     = (__bf16*)alloc((size_t)768 * 768 * 2);
    float*  z_t     = (float*) alloc((size_t)24 * 2048 * 4);
    __bf16* VT      = (__bf16*)alloc((size_t)768 * 4096 * 2);
    __bf16* out_pre = (__bf16*)alloc((size_t)4096 * 768 * 2);

    k_prep<<<512, 256, 0, stream>>>(x, Wv, Wp, xb, Wvb, Wpb, x_part);
    k_mid <<<288, 256, 0, stream>>>(xb, Wvb, x_part, Wk, Wq, VT, z_t);
    k_conv<<<384, 256, 0, stream>>>(z_t, VT, out_pre);
    k_out <<<192, 256, 0, stream>>>(out_pre, Wpb, bp, (float*)d_out);
}